// Round 4
// baseline (507.957 us; speedup 1.0000x reference)
//
#include <hip/hip_runtime.h>

// CustomAttention: out = softmax((x_t Wq^T + bq)(x_nt Wk^T + bk)^T) (x_nt Wv^T + bv)
// B=8, SQ=SKV=2048, D=1024. fp32 in/out, fp16 MFMA compute (fp32 accumulate).
//
// Round 6 == round 5 resubmitted (round-5 bench died to infra: "container
// failed twice", no counters; code audit found no hang/fault path).
//
// Design: GEMM K-loop is at the measured plain-HIP ceiling for K=1024 shapes
// (~848 TF, cf. m248 reference) -- 3 schedule variants all land there. So this
// round removes non-GEMM work instead, via a templated A-staging transform
// (reg-load early -> transform -> ds_write late, HBM latency hidden under MFMA):
//   ATRANS 0: A fp16, global_load_lds direct (QK -- unchanged verified path)
//   ATRANS 1: A fp32, fused cast->fp16    (projections; deletes 2 cast kernels)
//   ATRANS 2: A = S fp16, fused exp(S-m)*inv (PV; deletes softmax kernel; tiny
//             rowstat pre-pass computes per-row max & 1/sum)
// Plus XCD-aware block swizzle (SWZ) on QK/PV for L2 panel locality.
//
// Ring/sync invariants (unchanged from verified r4 K-loop):
//  - 4-slot LDS ring/operand, staging depth 3, ONE s_barrier per K=32 slice.
//  - end-of-slice vmcnt: ATRANS0: vmcnt(4) (4 gloads/slice in flight);
//    ATRANS1/2: vmcnt(2) (B-only gloads; A-loads are reg-path, auto-waited
//    by the compiler right before the transform -- after the MFMA cluster).
//  - A ds_writes drained by the per-slice lgkmcnt(0) before the barrier;
//    consumers read 2 barriers later.
//
// ws layout:
//  [0,64)    S16 (QK out)       [64,65) mrow  [65,66) srow
//  [128,160) Q16  [160,192) K16  [192,224) Vt16  [224,230) W*16

typedef _Float16 half8 __attribute__((ext_vector_type(8)));
typedef _Float16 half4v __attribute__((ext_vector_type(4)));
typedef float floatx4 __attribute__((ext_vector_type(4)));

__device__ __forceinline__ void async_copy16(const _Float16* g, _Float16* l) {
  __builtin_amdgcn_global_load_lds(
      (const __attribute__((address_space(1))) void*)g,
      (__attribute__((address_space(3))) void*)l,
      16, 0, 0);
}

// ---------------- cast fp32 -> fp16 (weights only now) ----------------
__global__ __launch_bounds__(256) void cast_f32_f16(const float* __restrict__ src,
                                                    _Float16* __restrict__ dst, long n) {
  long i = ((long)blockIdx.x * 256 + threadIdx.x) * 8;
  if (i >= n) return;
  float4 a = *(const float4*)(src + i);
  float4 b = *(const float4*)(src + i + 4);
  half8 h;
  h[0] = (_Float16)a.x; h[1] = (_Float16)a.y; h[2] = (_Float16)a.z; h[3] = (_Float16)a.w;
  h[4] = (_Float16)b.x; h[5] = (_Float16)b.y; h[6] = (_Float16)b.z; h[7] = (_Float16)b.w;
  *(half8*)(dst + i) = h;
}

// ---------------- fp16 BT GEMM, 256x256 tile, 1-barrier/slice pipeline -----
// C[m,n] = sum_k A[m,k]*B[n,k] (+bias[n])
// OMODE 0: fp16 out row-major + bias | 1: fp16 Vt[b][n][s] + bias
// OMODE 2: fp32 out per batch        | 3: fp16 out per batch (S scores)

#define GSLICE(KC, AFC, BFC, AFN, BFN)                                          \
  {                                                                             \
    const int kc_ = (KC);                                                       \
    int ks_ = kc_ + 3; if (ks_ > NK - 1) ks_ = NK - 1;                          \
    int pf_ = kc_ + 1; if (pf_ > NK - 1) pf_ = NK - 1;                          \
    _Float16* sa_ = Ar + (ks_ & 3) * 8192 + ldst;                               \
    _Float16* sb_ = Br + (ks_ & 3) * 8192 + ldst;                               \
    const long go_ = (long)ks_ * 32;                                            \
    floatx4 qa0_, qa1_, qb0_, qb1_; half8 ha_, hb_;                             \
    if (ATRANS == 0) {                                                          \
      async_copy16(Ah + go_, sa_);                                              \
      async_copy16(Ah + go_ + lK128, sa_ + 4096);                               \
    } else if (ATRANS == 1) {                                                   \
      qa0_ = *(const floatx4*)(Af + go_);                                       \
      qa1_ = *(const floatx4*)(Af + go_ + 4);                                   \
      qb0_ = *(const floatx4*)(Af + go_ + lK128);                               \
      qb1_ = *(const floatx4*)(Af + go_ + lK128 + 4);                           \
    } else {                                                                    \
      ha_ = *(const half8*)(Ah + go_);                                          \
      hb_ = *(const half8*)(Ah + go_ + lK128);                                  \
    }                                                                           \
    async_copy16(Bh + go_, sb_);                                                \
    async_copy16(Bh + go_ + lK128, sb_ + 4096);                                 \
    const _Float16* pa_ = Ar + (pf_ & 3) * 8192 + wm * 4096 + aoff;             \
    const _Float16* pb_ = Br + (pf_ & 3) * 8192 + wn * 2048 + aoff;             \
    _Pragma("unroll") for (int n = 0; n < 4; ++n)                               \
      BFN[n] = *(const half8*)(pb_ + n * 512);                                  \
    _Pragma("unroll") for (int i = 0; i < 8; ++i)                               \
      AFN[i] = *(const half8*)(pa_ + (i & 3) * 512 + (i >> 2) * 2048);          \
    __builtin_amdgcn_sched_barrier(0);                                          \
    __builtin_amdgcn_s_setprio(1);                                              \
    _Pragma("unroll") for (int i = 0; i < 8; ++i)                               \
      _Pragma("unroll") for (int n = 0; n < 4; ++n)                             \
        acc[i][n] = __builtin_amdgcn_mfma_f32_16x16x32_f16(AFC[i], BFC[n],      \
                                                           acc[i][n], 0, 0, 0); \
    __builtin_amdgcn_s_setprio(0);                                              \
    __builtin_amdgcn_sched_barrier(0);                                          \
    if (ATRANS == 1) {                                                          \
      half8 w0_, w1_;                                                           \
      _Pragma("unroll") for (int t = 0; t < 4; ++t) {                           \
        w0_[t] = (_Float16)qa0_[t]; w0_[4 + t] = (_Float16)qa1_[t];             \
        w1_[t] = (_Float16)qb0_[t]; w1_[4 + t] = (_Float16)qb1_[t]; }           \
      *(half8*)sa_ = w0_; *(half8*)(sa_ + 4096) = w1_;                          \
    } else if (ATRANS == 2) {                                                   \
      half8 w0_, w1_;                                                           \
      _Pragma("unroll") for (int t = 0; t < 8; ++t) {                           \
        w0_[t] = (_Float16)(__expf((float)ha_[t] - mA0) * sA0);                 \
        w1_[t] = (_Float16)(__expf((float)hb_[t] - mA1) * sA1); }               \
      *(half8*)sa_ = w0_; *(half8*)(sa_ + 4096) = w1_;                          \
    }                                                                           \
    asm volatile("s_waitcnt lgkmcnt(0)" ::: "memory");                          \
    __builtin_amdgcn_sched_barrier(0);                                          \
    if (ATRANS == 0) { asm volatile("s_waitcnt vmcnt(4)" ::: "memory"); }       \
    else             { asm volatile("s_waitcnt vmcnt(2)" ::: "memory"); }       \
    __builtin_amdgcn_s_barrier();                                               \
  }

template <int OMODE, int ATRANS, int SWZ>
__global__ __launch_bounds__(512, 2) void gemm256(const void* __restrict__ A,
                                                  const _Float16* __restrict__ Bm,
                                                  const float* __restrict__ bias,
                                                  const float* __restrict__ rowM,
                                                  const float* __restrict__ rowS,
                                                  void* __restrict__ out,
                                                  int K, int N,
                                                  long sA, long sB, long sO) {
  __shared__ __attribute__((aligned(16))) _Float16 lds[65536];
  _Float16* Ar = lds;
  _Float16* Br = lds + 32768;

  const int tid = threadIdx.x;
  const int lane = tid & 63;
  const int wave = tid >> 6;
  const int wm = wave >> 2;   // 0..1  (M half)
  const int wn = wave & 3;    // 0..3  (N quarter)
  const int frow = lane & 15;
  const int fq = (lane >> 4) & 3;
  const long bz = blockIdx.z;

  // XCD-aware bijective block swizzle: group output panels per XCD so each
  // XCD's private L2 holds its working set (QK: 2 Q + 4 K panels = 3 MB).
  int bx = blockIdx.x, by = blockIdx.y;
  if (SWZ == 1) {  // grid (8,8)
    int h = bx + 8 * by, g = h & 7, idx = h >> 3;
    bx = (g & 3) * 2 + (idx & 1);
    by = (g >> 2) * 4 + (idx >> 1);
  } else if (SWZ == 2) {  // grid (8,4)
    int h = bx + 8 * by, g = h & 7, idx = h >> 3;
    bx = (g & 3) * 2 + (idx & 1);
    by = (g >> 2) * 2 + (idx >> 1);
  }

  // Staging geometry (verified r4): chunk c = tid (+512j) -> lds row l=c>>3,
  // phys granule c&7, logical granule glog = (c&7)^(l&7); global row =
  // 2l + (glog>>2), k-granule = glog&3.
  const int glog = (tid & 7) ^ ((tid >> 3) & 7);
  const long sg = (long)(2 * (tid >> 3) + (glog >> 2)) * K + (glog & 3) * 8;
  const int ldst = tid * 8;
  const long lK128 = (long)K * 128;

  const _Float16* Ah = (ATRANS != 1) ? (const _Float16*)A + bz * sA + (long)bx * 256 * K + sg
                                     : nullptr;
  const float* Af = (ATRANS == 1) ? (const float*)A + bz * sA + (long)bx * 256 * K + sg
                                  : nullptr;
  const _Float16* Bh = Bm + bz * sB + (long)by * 256 * K + sg;

  // PV softmax stats: this thread stages the same 2 A-rows every slice.
  float mA0 = 0.f, sA0 = 0.f, mA1 = 0.f, sA1 = 0.f;
  if (ATRANS == 2) {
    const int rA0 = 2 * (tid >> 3) + (glog >> 2);
    const long gr = bz * 2048 + (long)bx * 256 + rA0;
    mA0 = rowM[gr]; sA0 = rowS[gr];
    mA1 = rowM[gr + 128]; sA1 = rowS[gr + 128];
  }

  // Fragment reads: g_phys = ((R&1)*4+fq) ^ (R>>1 & 7); frag bases are
  // 16-row-aligned -> swizzle key = frow>>1, lane-invariant across frags.
  const int gphys = ((frow & 1) * 4 + fq) ^ (frow >> 1);
  const int aoff = (frow >> 1) * 64 + gphys * 8;

  floatx4 acc[8][4];
#pragma unroll
  for (int m = 0; m < 8; ++m)
#pragma unroll
    for (int n = 0; n < 4; ++n) acc[m][n] = (floatx4){0.f, 0.f, 0.f, 0.f};

  const int NK = K >> 5;

  // Prologue: stage slices 0,1,2. A-transform paths run serially (once/block).
#pragma unroll
  for (int kp = 0; kp < 3; ++kp) {
    _Float16* sa = Ar + kp * 8192 + ldst;
    if (ATRANS == 0) {
      async_copy16(Ah + kp * 32, sa);
      async_copy16(Ah + kp * 32 + lK128, sa + 4096);
    } else if (ATRANS == 1) {
      floatx4 a0 = *(const floatx4*)(Af + kp * 32);
      floatx4 a1 = *(const floatx4*)(Af + kp * 32 + 4);
      floatx4 b0 = *(const floatx4*)(Af + kp * 32 + lK128);
      floatx4 b1 = *(const floatx4*)(Af + kp * 32 + lK128 + 4);
      half8 w0, w1;
#pragma unroll
      for (int t = 0; t < 4; ++t) {
        w0[t] = (_Float16)a0[t]; w0[4 + t] = (_Float16)a1[t];
        w1[t] = (_Float16)b0[t]; w1[4 + t] = (_Float16)b1[t];
      }
      *(half8*)sa = w0; *(half8*)(sa + 4096) = w1;
    } else {
      half8 h0 = *(const half8*)(Ah + kp * 32);
      half8 h1 = *(const half8*)(Ah + kp * 32 + lK128);
      half8 w0, w1;
#pragma unroll
      for (int t = 0; t < 8; ++t) {
        w0[t] = (_Float16)(__expf((float)h0[t] - mA0) * sA0);
        w1[t] = (_Float16)(__expf((float)h1[t] - mA1) * sA1);
      }
      *(half8*)sa = w0; *(half8*)(sa + 4096) = w1;
    }
    async_copy16(Bh + kp * 32, Br + kp * 8192 + ldst);
    async_copy16(Bh + kp * 32 + lK128, Br + kp * 8192 + ldst + 4096);
  }
  asm volatile("s_waitcnt lgkmcnt(0)" ::: "memory");
  asm volatile("s_waitcnt vmcnt(4)" ::: "memory");
  __builtin_amdgcn_s_barrier();

  // Prefetch slice 0 fragments.
  half8 afA[8], bfA[4], afB[8], bfB[4];
  {
    const _Float16* pa = Ar + wm * 4096 + aoff;
    const _Float16* pb = Br + wn * 2048 + aoff;
#pragma unroll
    for (int n = 0; n < 4; ++n) bfA[n] = *(const half8*)(pb + n * 512);
#pragma unroll
    for (int i = 0; i < 8; ++i) afA[i] = *(const half8*)(pa + (i & 3) * 512 + (i >> 2) * 2048);
  }
  asm volatile("s_waitcnt lgkmcnt(0)" ::: "memory");
  __builtin_amdgcn_sched_barrier(0);

  for (int kc = 0; kc < NK; kc += 2) {
    GSLICE(kc, afA, bfA, afB, bfB);
    GSLICE(kc + 1, afB, bfB, afA, bfA);
  }

  // Epilogue. acc[m][n][i] = C[wm*128 + m*16 + fq*4 + i][wn*64 + n*16 + frow]
  if (OMODE == 0 || OMODE == 1) {
#pragma unroll
    for (int n = 0; n < 4; ++n) {
      const int cg = by * 256 + wn * 64 + n * 16 + frow;
      const float bvv = bias[cg];
#pragma unroll
      for (int m = 0; m < 8; ++m) {
        const int rg = bx * 256 + wm * 128 + m * 16 + fq * 4;
        if (OMODE == 0) {
#pragma unroll
          for (int i = 0; i < 4; ++i)
            ((_Float16*)out)[(long)(rg + i) * N + cg] = (_Float16)(acc[m][n][i] + bvv);
        } else {
          const long bb = rg >> 11;
          const int s = rg & 2047;
          half4v hv;
#pragma unroll
          for (int i = 0; i < 4; ++i) hv[i] = (_Float16)(acc[m][n][i] + bvv);
          *(half4v*)((_Float16*)out + bb * (2048l * 1024) + (long)cg * 2048 + s) = hv;
        }
      }
    }
  } else {
#pragma unroll
    for (int n = 0; n < 4; ++n) {
      const int cg = by * 256 + wn * 64 + n * 16 + frow;
#pragma unroll
      for (int m = 0; m < 8; ++m) {
        const int rgl = bx * 256 + wm * 128 + m * 16 + fq * 4;
#pragma unroll
        for (int i = 0; i < 4; ++i) {
          if (OMODE == 2)
            ((float*)out + bz * sO)[(long)(rgl + i) * N + cg] = acc[m][n][i];
          else
            ((_Float16*)out + bz * sO)[(long)(rgl + i) * N + cg] = (_Float16)acc[m][n][i];
        }
      }
    }
  }
}

// ---------------- row stats: S fp16 [rows][2048] -> max, 1/sum -------------
__global__ __launch_bounds__(256) void rowstat(const _Float16* __restrict__ S,
                                               float* __restrict__ rowM,
                                               float* __restrict__ rowS) {
  const long row = blockIdx.x;
  const _Float16* src = S + row * 2048;
  const int tid = threadIdx.x;

  half8 v = ((const half8*)src)[tid];
  float f[8];
#pragma unroll
  for (int i = 0; i < 8; i++) f[i] = (float)v[i];

  float m = fmaxf(fmaxf(fmaxf(f[0], f[1]), fmaxf(f[2], f[3])),
                  fmaxf(fmaxf(f[4], f[5]), fmaxf(f[6], f[7])));
#pragma unroll
  for (int o = 32; o > 0; o >>= 1) m = fmaxf(m, __shfl_xor(m, o, 64));
  __shared__ float redm[4];
  if ((tid & 63) == 0) redm[tid >> 6] = m;
  __syncthreads();
  m = fmaxf(fmaxf(redm[0], redm[1]), fmaxf(redm[2], redm[3]));

  float s = 0.f;
#pragma unroll
  for (int i = 0; i < 8; i++) s += __expf(f[i] - m);
#pragma unroll
  for (int o = 32; o > 0; o >>= 1) s += __shfl_xor(s, o, 64);
  __shared__ float reds[4];
  if ((tid & 63) == 0) reds[tid >> 6] = s;
  __syncthreads();
  s = (reds[0] + reds[1]) + (reds[2] + reds[3]);

  if (tid == 0) {
    rowM[row] = m;
    rowS[row] = 1.f / s;
  }
}

extern "C" void kernel_launch(void* const* d_in, const int* in_sizes, int n_in,
                              void* d_out, int out_size, void* d_ws, size_t ws_size,
                              hipStream_t stream) {
  const float* target = (const float*)d_in[0];
  const float* non_target = (const float*)d_in[1];
  const float* Wq = (const float*)d_in[2];
  const float* bq = (const float*)d_in[3];
  const float* Wk = (const float*)d_in[4];
  const float* bk = (const float*)d_in[5];
  const float* Wv = (const float*)d_in[6];
  const float* bv = (const float*)d_in[7];

  char* ws = (char*)d_ws;
  const size_t MB = 1ull << 20;
  _Float16* S16 = (_Float16*)(ws);               // 64 MiB
  float* mrow = (float*)(ws + 64 * MB);          // 64 KiB
  float* srow = (float*)(ws + 65 * MB);          // 64 KiB
  _Float16* Q16 = (_Float16*)(ws + 128 * MB);    // 32 MiB
  _Float16* K16 = (_Float16*)(ws + 160 * MB);    // 32 MiB
  _Float16* Vt16 = (_Float16*)(ws + 192 * MB);   // 32 MiB
  _Float16* Wq16 = (_Float16*)(ws + 224 * MB);   // 2 MiB
  _Float16* Wk16 = (_Float16*)(ws + 226 * MB);   // 2 MiB
  _Float16* Wv16 = (_Float16*)(ws + 228 * MB);   // 2 MiB

  const long nW = 1024l * 1024;

  // 1. weight casts only (activation casts fused into projection staging)
  cast_f32_f16<<<512, 256, 0, stream>>>(Wq, Wq16, nW);
  cast_f32_f16<<<512, 256, 0, stream>>>(Wk, Wk16, nW);
  cast_f32_f16<<<512, 256, 0, stream>>>(Wv, Wv16, nW);

  // 2. projections (A = fp32 source, fused cast): [16384,1024] x [1024,1024]^T + bias
  gemm256<0, 1, 0><<<dim3(64, 4, 1), 512, 0, stream>>>(target, Wq16, bq, nullptr, nullptr,
                                                       Q16, 1024, 1024, 0, 0, 0);
  gemm256<0, 1, 0><<<dim3(64, 4, 1), 512, 0, stream>>>(non_target, Wk16, bk, nullptr, nullptr,
                                                       K16, 1024, 1024, 0, 0, 0);
  gemm256<1, 1, 0><<<dim3(64, 4, 1), 512, 0, stream>>>(non_target, Wv16, bv, nullptr, nullptr,
                                                       Vt16, 1024, 1024, 0, 0, 0);

  // 3. scores: per batch [2048,2048] = Q_b x K_b^T (fp16 out), XCD swizzle
  gemm256<3, 0, 1><<<dim3(8, 8, 8), 512, 0, stream>>>(Q16, K16, nullptr, nullptr, nullptr,
                                                      S16, 1024, 2048,
                                                      2048l * 1024, 2048l * 1024, 2048l * 2048);

  // 4. row stats (max, 1/sum) for fused softmax
  rowstat<<<16384, 256, 0, stream>>>(S16, mrow, srow);

  // 5. out: per batch [2048,1024] = softmax(S)_b x Vt_b^T (fp32 out), fused
  //    exp((S-m))*inv in A-staging, XCD swizzle
  gemm256<2, 2, 2><<<dim3(8, 4, 8), 512, 0, stream>>>(S16, Vt16, nullptr, mrow, srow,
                                                      (float*)d_out, 2048, 1024,
                                                      2048l * 2048, 1024l * 2048, 2048l * 1024);
}